// Round 14
// baseline (24534.956 us; speedup 1.0000x reference)
//
#include <hip/hip_runtime.h>

namespace {

constexpr int Vv=30000, Ll=400, Tt=145;
constexpr int SOS_TOK=1;
constexpr int NB=256, NT=512;
constexpr int RV=2000;              // vocab slice per worker (15 workers)

// ---- d_out used as scratch before decoder writes it (time-disjoint) ----
constexpr long SO_EMB = 0;                      // [6400][100]
constexpr long SO_GIF = SO_EMB + 6400L*100;     // [6400][450]
constexpr long SO_GIB = SO_GIF + 6400L*450;     // [6400][450]
constexpr long SO_ENC = SO_GIB + 6400L*450;     // [6400][300]
constexpr long SO_WCAT= SO_GIF;                 // [301][300] staged after encoder

// ---- ws float offsets ----
constexpr long OFF_M   =0;                      // [6400][200]
constexpr long OFF_N   =OFF_M+6400L*200;        // [6400][100]
constexpr long OFF_Q   =OFF_N+6400L*100;        // [6400]
constexpr long OFF_HENC=OFF_Q+6400;             // [2dir*16][150]
constexpr long OFF_H0  =OFF_HENC+4800;          // [16][200]
constexpr long OFF_OWN =OFF_H0+3200;            // [2par][16][512]: 0-99 pre,100 Zprev,101 wbscalePrev,104+ cd2
constexpr long OFF_WPS =OFF_OWN+2L*16*512;      // [2par][16][16] worker psums
constexpr long OFF_CD1 =OFF_WPS+2L*16*16;       // [2par][16][512]
constexpr long WS_F32_END=OFF_CD1+2L*16*512;
constexpr long PMAX_BYTE=((WS_F32_END*4+255)/256)*256;  // u64 [2par][16][16]
constexpr long IWS_BYTE =PMAX_BYTE+2L*16*16*8;
constexpr int ISVL=0, IGV=6400, IGLS=12800, IRG0=19216, INGR=19472; // ints end 19488
constexpr long BAR_BYTE =((IWS_BYTE+19488L*4+255)/256)*256;
// bar int indices
constexpr int FH=0;         // 256 setup flags
constexpr int FO=256;       // owner flags: FO + b*16
constexpr int FW=512;       // worker flags: FW + b*16 + w
constexpr int ABRT=768;
constexpr int BARN=832;

struct Args {
  const int* itok;
  const float* emb;
  const float* Wfih; const float* Wfhh; const float* bfih; const float* bfhh;
  const float* Wbih; const float* Wbhh; const float* bbih; const float* bbhh;
  const float* adW; const float* adb;
  const float* dWih; const float* dWhh; const float* dbih; const float* dbhh;
  const float* bilW; const float* bilb; const float* cw;
  const float* ptrW; const float* ptrb;
  const float* preW; const float* preb; const float* outb;
  float* out; float* ws; unsigned long long* pmax; int* iws; int* bar;
};

__device__ __forceinline__ float sigm(float x){ return 1.f/(1.f+expf(-x)); }
__device__ __forceinline__ unsigned long long packvi(float val, int v){
  return ((unsigned long long)__float_as_uint(val)<<32) | (unsigned)(~(unsigned)v);
}
__device__ __forceinline__ float ald(const float* p){
  return __hip_atomic_load(p, __ATOMIC_RELAXED, __HIP_MEMORY_SCOPE_AGENT); }
__device__ __forceinline__ void ast(float* p, float v){
  __hip_atomic_store(p, v, __ATOMIC_RELAXED, __HIP_MEMORY_SCOPE_AGENT); }
__device__ __forceinline__ unsigned long long aldu(const unsigned long long* p){
  return __hip_atomic_load(p, __ATOMIC_RELAXED, __HIP_MEMORY_SCOPE_AGENT); }
__device__ __forceinline__ void astu(unsigned long long* p, unsigned long long v){
  __hip_atomic_store(p, v, __ATOMIC_RELAXED, __HIP_MEMORY_SCOPE_AGENT); }
__device__ __forceinline__ int aldi(const int* p){
  return __hip_atomic_load(p, __ATOMIC_RELAXED, __HIP_MEMORY_SCOPE_AGENT); }
__device__ __forceinline__ void asti(int* p, int v){
  __hip_atomic_store(p, v, __ATOMIC_RELAXED, __HIP_MEMORY_SCOPE_AGENT); }

// ---- producer: drain all block stores, then one flag store ----
__device__ __forceinline__ void setFlagP(int* f, int v){
  asm volatile("s_waitcnt vmcnt(0) lgkmcnt(0)" ::: "memory");
  __syncthreads();
  if (threadIdx.x==0) asti(f, v);
}
// ---- single-line waits ----
__device__ __forceinline__ void waitOne(const int* f, int target, int* abrt){
  if (threadIdx.x==0){
    long it=0;
    while (aldi(f)<target){
      __builtin_amdgcn_s_sleep(4);
      if (++it>2000000L){ asti(abrt,1); break; }
      if ((it&255)==0 && aldi(abrt)!=0) break;
    }
  }
  __syncthreads();
}
__device__ __forceinline__ void wait15(const int* f, int target, int* abrt){
  if (threadIdx.x<16){
    long it=0;
    for(;;){
      int vv=(threadIdx.x>=1)? aldi(f+threadIdx.x) : 0x7FFFFFFF;
      if (__all(vv>=target)) break;
      __builtin_amdgcn_s_sleep(4);
      if (++it>2000000L){ asti(abrt,1); break; }
      if ((it&255)==0 && aldi(abrt)!=0) break;
    }
  }
  __syncthreads();
}
// ---- setup barrier: 64-lane flag scan + agent fences (r13, verified) ----
__device__ __forceinline__ void waitFlags(const int* flags, int n, int target, int* abrt){
  if (threadIdx.x<64){
    int lane=threadIdx.x;
    long it=0;
    for (;;){
      int mn=0x7FFFFFFF;
      for (int i=lane;i<n;i+=64){
        int v=aldi(flags+i);
        if (v<mn) mn=v;
      }
      if (__all(mn>=target)) break;
      __builtin_amdgcn_s_sleep(2);
      if (++it > 400000L){ asti(abrt,1); break; }
      if ((it&255)==0 && aldi(abrt)!=0) break;
    }
  }
  __syncthreads();
}
__device__ __forceinline__ void hbarF(const Args& a, int epoch){
  int* bar=a.bar;
  asm volatile("s_waitcnt vmcnt(0) lgkmcnt(0)" ::: "memory");
  __syncthreads();
  if (threadIdx.x==0){
    __builtin_amdgcn_fence(__ATOMIC_RELEASE, "agent");
    asti(bar+FH+(int)blockIdx.x, epoch);
  }
  waitFlags(bar+FH, NB, epoch, bar+ABRT);
  if (threadIdx.x==0)
    __builtin_amdgcn_fence(__ATOMIC_ACQUIRE, "agent");
  __syncthreads();
}

// ---- per-b bitonic sort -> scatter group structures + range table ----
__device__ void sortB(const Args& a, int b, char* smem){
  int tid=threadIdx.x;
  int* key=(int*)smem;
  key[tid] = (tid<Ll)? (a.itok[tid*16+b]*Ll + tid) : 0x7FFFFFFF;
  __syncthreads();
  for (int k=2;k<=512;k<<=1){
    for (int j=k>>1;j>0;j>>=1){
      int ixj = tid^j;
      if (ixj>tid){
        int x=key[tid], y=key[ixj];
        bool up = ((tid&k)==0);
        if ((x>y)==up){ key[tid]=y; key[ixj]=x; }
      }
      __syncthreads();
    }
  }
  int* ngS=(int*)(smem+2048);
  if (tid==0){
    int* svl=a.iws+ISVL+b*400; int* gvv=a.iws+IGV+b*400;
    int* gls=a.iws+IGLS+b*401;
    int ng=0, prev=-1;
    for (int i=0;i<400;i++){
      int kk=key[i]; int tok=kk/400, l=kk-tok*400;
      svl[i]=l;
      if (tok!=prev){ gvv[ng]=tok; gls[ng]=i; ng++; prev=tok; }
    }
    gls[ng]=400;
    a.iws[INGR+b]=ng;
    ngS[0]=ng;
  }
  __syncthreads();
  int ng=ngS[0];
  const int* gvv=a.iws+IGV+b*400;
  for (int rr=tid;rr<16;rr+=NT){
    int target=(rr<15)? rr*RV : 0x7FFFFFFF;
    int lo=0,hi=ng;
    while(lo<hi){ int mid=(lo+hi)>>1; if (gvv[mid]<target) lo=mid+1; else hi=mid; }
    a.iws[IRG0+b*16+rr]=lo;
  }
}

// ---- LDS-tiled GEMM: MODE 0: gi ; MODE 1: M/N/Q (r13, verified) ----
template<int MODE>
__device__ void tileGemm(const Args& a, char* smem){
  float* Xl=(float*)smem;            // [64][100]
  float* Wl=(float*)(smem+25600);    // [64][100]
  const int K   = MODE? 300 : 100;
  const int NC  = MODE? 301 : 900;
  const int nCT = MODE? 5 : 15;
  const int nTiles = 100*nCT;
  const float* X = a.out + (MODE? SO_ENC : SO_EMB);
  int ty=threadIdx.x>>4, tx=threadIdx.x&15;
  for (int tile=blockIdx.x; tile<nTiles; tile+=NB){
    int rt=tile%100, ct=tile/100;
    int r0=rt*64, c0=ct*64;
    float acc[2][4];
    #pragma unroll
    for (int i=0;i<2;i++){
      #pragma unroll
      for (int j=0;j<4;j++) acc[i][j]=0.f;
    }
    for (int k0=0;k0<K;k0+=100){
      for (int i=threadIdx.x;i<1600;i+=NT){
        int rr=i/25, e4=i%25;
        ((float4*)Xl)[rr*25+e4] = *((const float4*)(X + (long)(r0+rr)*K + k0) + e4);
      }
      for (int i=threadIdx.x;i<1600;i+=NT){
        int rr=i/25, e4=i%25; int c=c0+rr;
        float4 w={0.f,0.f,0.f,0.f};
        if (c<NC){
          const float* wr;
          if (MODE==0) wr = (c<450)? (a.Wfih + (long)c*100) : (a.Wbih + (long)(c-450)*100);
          else         wr = a.out + SO_WCAT + (long)c*300 + k0;
          w = *((const float4*)wr + e4);
        }
        ((float4*)Wl)[rr*25+e4]=w;
      }
      __syncthreads();
      for (int k4=0;k4<25;k4++){
        float4 a4[2], b4[4];
        #pragma unroll
        for (int i=0;i<2;i++) a4[i]=((float4*)Xl)[(ty*2+i)*25+k4];
        #pragma unroll
        for (int j=0;j<4;j++) b4[j]=((float4*)Wl)[(tx*4+j)*25+k4];
        #pragma unroll
        for (int i=0;i<2;i++){
          #pragma unroll
          for (int j=0;j<4;j++){
            acc[i][j] += a4[i].x*b4[j].x;
            acc[i][j] += a4[i].y*b4[j].y;
            acc[i][j] += a4[i].z*b4[j].z;
            acc[i][j] += a4[i].w*b4[j].w;
          }
        }
      }
      __syncthreads();
    }
    #pragma unroll
    for (int i=0;i<2;i++){
      #pragma unroll
      for (int j=0;j<4;j++){
        int r=r0+ty*2+i, c=c0+tx*4+j;
        if (c<NC){
          if (MODE==0){
            int dir=c/450, cc=c-dir*450;
            float v=acc[i][j] + (dir? a.bbih : a.bfih)[cc];
            a.out[(dir?SO_GIB:SO_GIF) + (long)r*450 + cc]=v;
          } else {
            if (c<200)      a.ws[OFF_M + (long)r*200 + c]=acc[i][j];
            else if (c<300) a.ws[OFF_N + (long)r*100 + (c-200)]=acc[i][j];
            else            a.ws[OFF_Q + r]=acc[i][j];
          }
        }
      }
    }
  }
}

// ---- encoder (r13, verified) ----
__device__ void encoderPhase(const Args& a, int bid, char* smem){
  int tid=threadIdx.x;
  int dir=bid>>4, b=bid&15;
  float* hbuf=(float*)smem;           // [2][192]
  float* gbuf=(float*)(smem+2048);    // [2][452]
  float* pacc=(float*)(smem+8192);    // [9][152]
  const float* Whh = dir? a.Wbhh : a.Wfhh;
  const float* bhh = dir? a.bbhh : a.bfhh;
  const float* giBase = a.out + (dir? SO_GIB : SO_GIF);
  int ks=tid/150; int j=tid-ks*150;
  bool act = (ks<3);
  float w[3][50];
  if (act){
    #pragma unroll
    for (int g=0;g<3;g++)
      for (int k=0;k<50;k++)
        w[g][k]=Whh[(long)(g*150+j)*150 + ks*50 + k];
  }
  float b0=0,b1=0,b2=0;
  if (act && ks==0){ b0=bhh[j]; b1=bhh[150+j]; b2=bhh[300+j]; }
  for (int i=tid;i<192;i+=NT) hbuf[i]=0.f;
  {
    int l0 = dir? 399 : 0;
    for (int i=tid;i<450;i+=NT) gbuf[i]=giBase[((long)l0*16+b)*450+i];
  }
  __syncthreads();
  for (int s=0;s<400;s++){
    int p=s&1;
    int l=dir? 399-s : s;
    if (tid>=450 && s+1<400){
      int ln=dir? 399-(s+1) : s+1;
      for (int i=tid-450;i<450;i+=62) gbuf[(p^1)*452+i]=giBase[((long)ln*16+b)*450+i];
    }
    if (act){
      float ar=0.f, az=0.f, an=0.f;
      const float* hr=hbuf + p*192 + ks*64;
      #pragma unroll
      for (int k4=0;k4<12;k4++){
        float4 h4=*(const float4*)(hr + k4*4);
        ar+=h4.x*w[0][k4*4+0]; ar+=h4.y*w[0][k4*4+1]; ar+=h4.z*w[0][k4*4+2]; ar+=h4.w*w[0][k4*4+3];
        az+=h4.x*w[1][k4*4+0]; az+=h4.y*w[1][k4*4+1]; az+=h4.z*w[1][k4*4+2]; az+=h4.w*w[1][k4*4+3];
        an+=h4.x*w[2][k4*4+0]; an+=h4.y*w[2][k4*4+1]; an+=h4.z*w[2][k4*4+2]; an+=h4.w*w[2][k4*4+3];
      }
      {
        float h48=hr[48], h49=hr[49];
        ar+=h48*w[0][48]+h49*w[0][49];
        az+=h48*w[1][48]+h49*w[1][49];
        an+=h48*w[2][48]+h49*w[2][49];
      }
      pacc[(ks*3+0)*152+j]=ar;
      pacc[(ks*3+1)*152+j]=az;
      pacc[(ks*3+2)*152+j]=an;
    }
    __syncthreads();
    if (act && ks==0){
      float ar=pacc[(0*3+0)*152+j]+pacc[(1*3+0)*152+j]+pacc[(2*3+0)*152+j];
      float az=pacc[(0*3+1)*152+j]+pacc[(1*3+1)*152+j]+pacc[(2*3+1)*152+j];
      float an=pacc[(0*3+2)*152+j]+pacc[(1*3+2)*152+j]+pacc[(2*3+2)*152+j];
      const float* gi=gbuf + p*452;
      float r=sigm(gi[j]      + ar + b0);
      float z=sigm(gi[150+j]  + az + b1);
      float n=tanhf(gi[300+j] + r*(an + b2));
      int slot=(j/50)*64 + (j%50);
      float hold=hbuf[p*192+slot];
      float hv=(1.f-z)*n + z*hold;
      hbuf[(p^1)*192+slot]=hv;
      a.out[SO_ENC + ((long)l*16+b)*300 + dir*150 + j]=hv;
      if (s==399) a.ws[OFF_HENC + ((long)dir*16+b)*150 + j]=hv;
    }
    __syncthreads();
  }
}

// ======================= decoder: per-b pipelines =======================
// Owner LDS: hw[2][200]@0, cover[400]@1600, exl[400]@3200, cd2L[400]@4800,
//            xw[100]@6400, msf@6800 (0=Z,1=za,2=pfac,3=pp), msi@6864 (tok),
//            redU@6992 (u64[8])
__device__ void ownerStep(const Args& a, int b, int t, char* smem){
  int tid=threadIdx.x;
  float* hw   =(float*)smem;
  float* cover=(float*)(smem+1600);
  float* exl  =(float*)(smem+3200);
  float* cd2L =(float*)(smem+4800);
  float* xw   =(float*)(smem+6400);
  float* msf  =(float*)(smem+6800);
  int*   msi  =(int*)(smem+6864);
  unsigned long long* redU=(unsigned long long*)(smem+6992);
  int par=t&1, par1=par^1;
  float* own=a.ws+OFF_OWN+((long)par*16+b)*512;
  float* hOld=hw+par*200; float* hNew=hw+par1*200;
  if (t==0){
    if (tid==0) msi[0]=SOS_TOK;
    __syncthreads();
  } else {
    // Z + gen-best from 15 workers (psum: ONE 64B line)
    const float* wps=a.ws+OFF_WPS+((long)par1*16+b)*16;
    const unsigned long long* wpm=a.pmax+((long)par1*16+b)*16;
    if (tid<16){
      float s=(tid<15)? ald(wps+tid) : 0.f;
      #pragma unroll
      for (int off=8;off;off>>=1) s+=__shfl_xor(s,off,16);
      unsigned long long pm=(tid<15)? aldu(wpm+tid) : 0ull;
      float Z=s;
      unsigned long long pk=0ull;
      if (pm!=0ull){
        float ev=__uint_as_float((unsigned)(pm>>32));
        int v=(int)(~(unsigned)(pm&0xFFFFFFFFull));
        pk=packvi(ev/Z, v);
      }
      #pragma unroll
      for (int off=8;off;off>>=1){ unsigned long long o=__shfl_xor(pk,off,16); if(o>pk)pk=o; }
      if (tid==0){ msf[0]=Z; redU[7]=pk; }
    }
    __syncthreads();
    float Z=msf[0];
    // pointer candidates + tok
    if (tid<64){
      const float* cd1=a.ws+OFF_CD1+((long)par1*16+b)*512;
      int ng=a.iws[INGR+b];
      const int* gvv=a.iws+IGV+b*400;
      unsigned long long best=0ull;
      for (int g=tid; g<ng; g+=64){
        float val=ald(cd1+g)/Z + cd2L[g];
        unsigned long long pk=packvi(val, gvv[g]);
        if (pk>best) best=pk;
      }
      #pragma unroll
      for (int off=32;off;off>>=1){ unsigned long long o=__shfl_xor(best,off,64); if(o>best)best=o; }
      if (tid==0){
        if (redU[7]>best) best=redU[7];
        msi[0]=(int)(~(unsigned)(best&0xFFFFFFFFull));
      }
    }
    // cover update (attn(t-1) = exl/zaPrev) + publish Zprev/wbscalePrev
    if (tid<400) cover[tid] += exl[tid]/msf[1];
    if (tid==400) ast(own+100, Z);
    if (tid==401) ast(own+101, (1.f-msf[3])/Z);
    __syncthreads();
  }
  int tok=msi[0];
  if (tid<100) xw[tid]=a.emb[(long)tok*100+tid];
  __syncthreads();
  // GRU -> hNew
  {
    int unit=tid>>3, lane=tid&7;
    for (int p4=0;p4<4;p4++){
      int j=p4*64+unit;
      if (j<200){
        float air=0,aiz=0,ain=0,ahr=0,ahz=0,ahn=0;
        for (int k=lane;k<100;k+=8){
          float xv=xw[k];
          air+=xv*a.dWih[(long)j*100+k];
          aiz+=xv*a.dWih[(long)(200+j)*100+k];
          ain+=xv*a.dWih[(long)(400+j)*100+k];
        }
        for (int k=lane;k<200;k+=8){
          float hv=hOld[k];
          ahr+=hv*a.dWhh[(long)j*200+k];
          ahz+=hv*a.dWhh[(long)(200+j)*200+k];
          ahn+=hv*a.dWhh[(long)(400+j)*200+k];
        }
        #pragma unroll
        for (int off=4;off;off>>=1){
          air+=__shfl_xor(air,off,8); aiz+=__shfl_xor(aiz,off,8); ain+=__shfl_xor(ain,off,8);
          ahr+=__shfl_xor(ahr,off,8); ahz+=__shfl_xor(ahz,off,8); ahn+=__shfl_xor(ahn,off,8);
        }
        if (lane==0){
          float r=sigm(air + a.dbih[j]     + ahr + a.dbhh[j]);
          float z=sigm(aiz + a.dbih[200+j] + ahz + a.dbhh[200+j]);
          float n=tanhf(ain + a.dbih[400+j] + r*(ahn + a.dbhh[400+j]));
          hNew[j]=(1.f-z)*n + z*hOld[j];
        }
      }
    }
  }
  __syncthreads();
  // energies -> exl (all 400 l)
  {
    int unit=tid>>3, lane=tid&7;
    for (int l=unit;l<400;l+=64){
      const float* Mr=a.ws+OFF_M+(long)(l*16+b)*200;
      float acc=0.f;
      for (int k=lane;k<200;k+=8) acc+=hNew[k]*Mr[k];
      #pragma unroll
      for (int off=4;off;off>>=1) acc+=__shfl_xor(acc,off,8);
      if (lane==0){
        float en=acc + a.bilb[0] + a.cw[0]*logf(cover[l]+1e-31f);
        exl[l]=expf(en);
      }
    }
  }
  __syncthreads();
  // za
  if (tid<64){
    float s=0.f;
    for (int l=tid;l<400;l+=64) s+=exl[l];
    #pragma unroll
    for (int off=32;off;off>>=1) s+=__shfl_xor(s,off,64);
    if (tid==0) msf[1]=s;
  }
  __syncthreads();
  float za=msf[1];
  // ctx + pre + pp
  {
    int unit=tid>>2, lane=tid&3;
    if (unit<=100){
      float ctx=0.f, ph=0.f;
      if (unit<100){
        for (int l=lane;l<400;l+=4) ctx+=exl[l]*a.ws[OFF_N+(long)(l*16+b)*100+unit];
      } else {
        for (int l=lane;l<400;l+=4) ctx+=exl[l]*a.ws[OFF_Q+l*16+b];
      }
      const float* w2=(unit<100)? (a.preW+(long)unit*500) : a.ptrW;
      for (int k=lane;k<200;k+=4) ph+=hNew[k]*w2[k];
      #pragma unroll
      for (int off=2;off;off>>=1){ ctx+=__shfl_xor(ctx,off,4); ph+=__shfl_xor(ph,off,4); }
      if (lane==0){
        if (unit<100) ast(own+unit, ctx/za + ph + a.preb[unit]);
        else {
          float pp=sigm(ctx/za + ph + a.ptrb[0]);
          msf[3]=pp; msf[2]=pp/(1.f-pp);
        }
      }
    }
  }
  __syncthreads();
  // cd2 (publish + keep)
  {
    int ng=a.iws[INGR+b];
    const int* gls=a.iws+IGLS+b*401; const int* svl=a.iws+ISVL+b*400;
    float pfac=msf[2];
    for (int g=tid;g<ng;g+=NT){
      float gs=0.f;
      for (int i=gls[g];i<gls[g+1];i++) gs+=exl[svl[i]];
      float val=pfac*gs/za;
      cd2L[g]=val;
      ast(own+104+g, val);
    }
  }
  setFlagP(a.bar+FO+b*16, t+1);
}

__device__ void ownerTail(const Args& a, int b, char* smem){
  int tid=threadIdx.x;
  float* msf=(float*)(smem+6800);
  int parT=(Tt-1)&1;   // 0
  const float* wps=a.ws+OFF_WPS+((long)parT*16+b)*16;
  if (tid<16){
    float s=(tid<15)? ald(wps+tid) : 0.f;
    #pragma unroll
    for (int off=8;off;off>>=1) s+=__shfl_xor(s,off,16);
    if (tid==0) msf[0]=s;
  }
  __syncthreads();
  if (tid==0){
    float Z=msf[0];
    float* ownT=a.ws+OFF_OWN+((long)(Tt&1)*16+b)*512;
    ast(ownT+100, Z);
    ast(ownT+101, (1.f-msf[3])/Z);
  }
  setFlagP(a.bar+FO+b*16, Tt+1);
}

// Worker LDS: expBuf[2][2048]@0 (16KB), preS[100]@16384, scl@16804,
//             redF[8]@16868, redU u64[8]@16936
__device__ void workerWb(const Args& a, int b, int w, int t, char* smem){
  int tid=threadIdx.x;
  int r=w-1, V0=r*RV;
  int par=t&1, par1=par^1;
  float* expP=(float*)smem + par1*2048;
  float* scl =(float*)(smem+16804);
  const float* own=a.ws+OFF_OWN+((long)par*16+b)*512;
  if (tid==100) scl[0]=ald(own+100);
  if (tid==101) scl[1]=ald(own+101);
  __syncthreads();
  float Zprev=scl[0], wbs=scl[1];
  const float* cd2p=a.ws+OFF_OWN+((long)par1*16+b)*512+104;
  const int* rg0=a.iws+IRG0+b*16; const int* gvv=a.iws+IGV+b*400;
  int g0=rg0[r], g1=rg0[r+1];
  for (int g=g0+tid; g<g1; g+=NT)
    expP[gvv[g]-V0] += ald(cd2p+g)*Zprev;
  __syncthreads();
  float* row=a.out + ((long)(t-1)*16+b)*30000 + V0;
  for (int u=tid;u<RV;u+=NT) row[u]=expP[u]*wbs;
  __syncthreads();
}

__device__ void workerStep(const Args& a, int b, int w, int t, char* smem){
  int tid=threadIdx.x;
  int r=w-1, V0=r*RV;
  int par=t&1;
  float* expB=(float*)smem + par*2048;
  float* preS=(float*)(smem+16384);
  float* redF=(float*)(smem+16868);
  unsigned long long* redU=(unsigned long long*)(smem+16936);
  const float* own=a.ws+OFF_OWN+((long)par*16+b)*512;
  if (tid<100) preS[tid]=ald(own+tid);
  __syncthreads();
  if (t>0) workerWb(a,b,w,t,smem);
  // logits over slice
  float4 preg[25];
  {
    const float4* p4=(const float4*)preS;
    #pragma unroll
    for (int e=0;e<25;e++) preg[e]=p4[e];
  }
  const float4* emb4=(const float4*)a.emb;
  float s=0.f; unsigned long long m=0ull;
  for (int u=tid;u<RV;u+=NT){
    int v=V0+u;
    float acc=a.outb[v];
    const float4* er=emb4 + (long)v*25;
    #pragma unroll
    for (int e=0;e<25;e++){
      float4 A=er[e], Bv=preg[e];
      acc += A.x*Bv.x + A.y*Bv.y + A.z*Bv.z + A.w*Bv.w;
    }
    float ex=expf(acc);
    expB[u]=ex;
    s+=ex;
    unsigned long long pk=packvi(ex, v);
    if (pk>m) m=pk;
  }
  #pragma unroll
  for (int off=32;off;off>>=1){
    s+=__shfl_xor(s,off,64);
    unsigned long long o=__shfl_xor(m,off,64);
    if (o>m) m=o;
  }
  if ((tid&63)==0){ redF[tid>>6]=s; redU[tid>>6]=m; }
  __syncthreads();
  if (tid==0){
    float ss=0.f; unsigned long long mm=0ull;
    for (int i=0;i<8;i++){ ss+=redF[i]; if (redU[i]>mm) mm=redU[i]; }
    ast(a.ws+OFF_WPS+((long)par*16+b)*16+(w-1), ss);
    astu(a.pmax+((long)par*16+b)*16+(w-1), mm);
  }
  // cd1 for groups in range
  {
    const int* rg0=a.iws+IRG0+b*16; const int* gvv=a.iws+IGV+b*400;
    int g0=rg0[r], g1=rg0[r+1];
    float* cd1=a.ws+OFF_CD1+((long)par*16+b)*512;
    for (int g=g0+tid; g<g1; g+=NT)
      ast(cd1+g, expB[gvv[g]-V0]);
  }
  setFlagP(a.bar+FW+b*16+w, t+1);
}

__global__ void kInitBar(int* bar){
  for (int i=threadIdx.x;i<BARN;i+=1024) bar[i]=0;
}

__global__ __launch_bounds__(NT,1) void mega(Args a){
  __shared__ __align__(16) char smem[53248];
  int bid=blockIdx.x, tid=threadIdx.x;
  int* bar=a.bar;
  int* abrt=bar+ABRT;

  // ---- P0a: sort (0..15) | emb gather (16..255) ----
  if (bid<16){
    sortB(a,bid,smem);
  } else {
    for (long i=(long)(bid-16)*NT+tid; i<640000; i+=240L*NT){
      long pair=i/100; int e=(int)(i-pair*100);
      a.out[SO_EMB+i]=a.emb[(long)a.itok[pair]*100+e];
    }
  }
  hbarF(a,1);
  // ---- P0b: gi GEMM ----
  tileGemm<0>(a,smem);
  hbarF(a,2);
  // ---- P1: encoder ----
  if (bid<32) encoderPhase(a,bid,smem);
  hbarF(a,3);
  // ---- P2a: stage WCAT + adapter h0 ----
  for (long i=(long)bid*NT+tid; i<90300; i+=(long)NB*NT){
    int rr=(int)(i/300), k=(int)(i-(long)rr*300);
    float v;
    if (rr<200)      v=a.bilW[(long)rr*300+k];
    else if (rr<300) v=a.preW[(long)(rr-200)*500+200+k];
    else             v=a.ptrW[200+k];
    a.out[SO_WCAT+i]=v;
  }
  if (bid>=32 && bid<48){
    int b=bid-32;
    int unit=tid>>1, lane=tid&1;
    if (unit<200){
      int j=unit;
      const float* w=a.adW+(long)j*300 + lane*150;
      const float* hh=a.ws+OFF_HENC + ((long)lane*16+b)*150;
      float acc=0.f;
      for (int e=0;e<150;e++) acc+=hh[e]*w[e];
      acc+=__shfl_xor(acc,1,2);
      if (lane==0) a.ws[OFF_H0 + b*200 + j]=acc + a.adb[j];
    }
  }
  hbarF(a,4);
  // ---- P2b: M/N/Q GEMM ----
  tileGemm<1>(a,smem);
  hbarF(a,5);   // wb+inv: all L2s clean+invalid before decoder

  // ---- decoder: 16 independent per-b pipelines ----
  int grp=bid>>4, w=bid&15;
  if (w==0){
    // owner persistent LDS init
    float* hw=(float*)smem;
    float* cover=(float*)(smem+1600);
    for (int i=tid;i<200;i+=NT){ hw[i]=a.ws[OFF_H0+grp*200+i]; hw[200+i]=0.f; }
    for (int i=tid;i<400;i+=NT) cover[i]=0.f;
    __syncthreads();
    for (int t=0;t<Tt;t++){
      if (t>0) wait15(bar+FW+grp*16, t, abrt);
      ownerStep(a,grp,t,smem);
    }
    wait15(bar+FW+grp*16, Tt, abrt);
    ownerTail(a,grp,smem);
  } else {
    for (int t=0;t<Tt;t++){
      waitOne(bar+FO+grp*16, t+1, abrt);
      workerStep(a,grp,w,t,smem);
    }
    waitOne(bar+FO+grp*16, Tt+1, abrt);
    // final row Tt-1: pretend step Tt (par=1), expP = parity 0
    workerWb(a,grp,w,Tt,smem);
  }
}

} // namespace

extern "C" void kernel_launch(void* const* d_in, const int* in_sizes, int n_in,
                              void* d_out, int out_size, void* d_ws, size_t ws_size,
                              hipStream_t stream) {
  Args a;
  a.itok=(const int*)d_in[0];
  a.emb =(const float*)d_in[1];
  a.Wfih=(const float*)d_in[2]; a.Wfhh=(const float*)d_in[3];
  a.bfih=(const float*)d_in[4]; a.bfhh=(const float*)d_in[5];
  a.Wbih=(const float*)d_in[6]; a.Wbhh=(const float*)d_in[7];
  a.bbih=(const float*)d_in[8]; a.bbhh=(const float*)d_in[9];
  a.adW =(const float*)d_in[10]; a.adb=(const float*)d_in[11];
  a.dWih=(const float*)d_in[12]; a.dWhh=(const float*)d_in[13];
  a.dbih=(const float*)d_in[14]; a.dbhh=(const float*)d_in[15];
  a.bilW=(const float*)d_in[16]; a.bilb=(const float*)d_in[17];
  a.cw  =(const float*)d_in[18];
  a.ptrW=(const float*)d_in[19]; a.ptrb=(const float*)d_in[20];
  a.preW=(const float*)d_in[21]; a.preb=(const float*)d_in[22];
  a.outb=(const float*)d_in[23];
  a.out =(float*)d_out;
  a.ws  =(float*)d_ws;
  a.pmax=(unsigned long long*)((char*)d_ws + PMAX_BYTE);
  a.iws =(int*)((char*)d_ws + IWS_BYTE);
  a.bar =(int*)((char*)d_ws + BAR_BYTE);
  // ws usage ~8.0 MB (prior rounds demonstrated >= 9.4 MB available)

  hipError_t e0 = hipSuccess; (void)e0;
  kInitBar<<<dim3(1),dim3(1024),0,stream>>>(a.bar);
  void* kargs[] = { (void*)&a };
  e0 = hipLaunchCooperativeKernel(reinterpret_cast<const void*>(mega),
                                  dim3(NB), dim3(NT), kargs, 0, stream);
}